// Round 3
// baseline (7158.384 us; speedup 1.0000x reference)
//
#include <hip/hip_runtime.h>
#include <cstddef>

#define U_DIM 512
#define T_DIM 2048
#define B_DIM 32
#define F_DIM 1024
#define M_DIM (B_DIM * T_DIM)
#define NBLK 8               // blocks per batch
#define UB (U_DIM / NBLK)    // 64 u-states per block

// ---------------------------------------------------------------------------
// GEMM: potentials[m][n] = sum_k x[m][k]*W[k][n] + b[n] (+ boundary at t=0/T-1)
// fp32 vector-ALU (no fp32 MFMA on CDNA4). 128x64 tile, 256 threads, 8x4 micro.
// (unchanged — known good, ~1.2 ms)
// ---------------------------------------------------------------------------
#define BM 128
#define BN 64
#define BK 16

__global__ __launch_bounds__(256) void gemm_kernel(
    const float* __restrict__ x, const float* __restrict__ W,
    const float* __restrict__ bias, const float* __restrict__ lb,
    const float* __restrict__ rb, float* __restrict__ out)
{
  __shared__ float As[BK][BM + 4];
  __shared__ float Bs[BK][BN];
  const int m0 = blockIdx.x * BM;
  const int n0 = blockIdx.y * BN;
  const int tid = threadIdx.x;
  const int tx = tid & 15;
  const int ty = tid >> 4;

  float acc[8][4];
#pragma unroll
  for (int i = 0; i < 8; ++i)
#pragma unroll
    for (int j = 0; j < 4; ++j) acc[i][j] = 0.f;

  for (int k0 = 0; k0 < F_DIM; k0 += BK) {
#pragma unroll
    for (int i = 0; i < 2; ++i) {
      int id = i * 256 + tid;
      int row = id >> 2;
      int c4 = (id & 3) << 2;
      float4 a = *(const float4*)(x + (size_t)(m0 + row) * F_DIM + k0 + c4);
      As[c4 + 0][row] = a.x;
      As[c4 + 1][row] = a.y;
      As[c4 + 2][row] = a.z;
      As[c4 + 3][row] = a.w;
    }
    {
      int krow = tid >> 4;
      int c4 = (tid & 15) << 2;
      *(float4*)(&Bs[krow][c4]) =
          *(const float4*)(W + (size_t)(k0 + krow) * U_DIM + n0 + c4);
    }
    __syncthreads();
#pragma unroll
    for (int k = 0; k < BK; ++k) {
      float a[8], bb[4];
#pragma unroll
      for (int i = 0; i < 8; ++i) a[i] = As[k][ty * 8 + i];
#pragma unroll
      for (int j = 0; j < 4; ++j) bb[j] = Bs[k][tx * 4 + j];
#pragma unroll
      for (int i = 0; i < 8; ++i)
#pragma unroll
        for (int j = 0; j < 4; ++j) acc[i][j] += a[i] * bb[j];
    }
    __syncthreads();
  }

#pragma unroll
  for (int i = 0; i < 8; ++i) {
    int m = m0 + ty * 8 + i;
    int t = m & (T_DIM - 1);
    float4 o;
#pragma unroll
    for (int j = 0; j < 4; ++j) {
      int n = n0 + tx * 4 + j;
      float v = acc[i][j] + bias[n];
      if (t == 0) v += lb[n];
      if (t == T_DIM - 1) v += rb[n];
      ((float*)&o)[j] = v;
    }
    *(float4*)(out + (size_t)m * U_DIM + n0 + tx * 4) = o;
  }
}

// ---------------------------------------------------------------------------
// aux: copy transitions to output tail, build transposed TrT[u][v] in ws,
// write sequence_lengths.
// ---------------------------------------------------------------------------
__global__ void aux_kernel(const float* __restrict__ tr, float* __restrict__ out_tr,
                           float* __restrict__ trT, float* __restrict__ seqlen)
{
  int idx = blockIdx.x * blockDim.x + threadIdx.x;
  if (idx < U_DIM * U_DIM) {
    float v = tr[idx];
    out_tr[idx] = v;
    int r = idx >> 9;   // v
    int c = idx & 511;  // u
    trT[(size_t)c * U_DIM + r] = v;
  }
  if (idx < B_DIM) seqlen[idx] = (float)T_DIM;
}

// zero the packed state buffer (tags!) and done-flags (ws is poisoned)
__global__ void init_kernel(unsigned long long* __restrict__ statePk,
                            unsigned int* __restrict__ flags)
{
  int i = blockIdx.x * blockDim.x + threadIdx.x;
  if (i < 2 * B_DIM * U_DIM) statePk[i] = 0ull;
  if (i < B_DIM * NBLK) flags[i] = 0u;
}

// ---------------------------------------------------------------------------
// Viterbi forward scan, full-chip: 256 blocks = 8 u-slice blocks x 32 batches.
// blockIdx: b = blk & 31, j = blk >> 5 (u-slice).
// 512 threads: u_local = tid>>3 (64 u's), vseg = tid&7.
// trT slice held in 16 float4 regs per thread (loaded once).
//
// Sync protocol v3 — SELF-TAGGED state words (data IS the flag):
//  * producer (vseg==0 lane of each u) packs {tag=t (hi32), value (lo32)}
//    into one u64 and fire-and-forget relaxed-agent (sc1) stores it into
//    statePk[t&1][b][u]. No vmcnt drain, no separate flag, no fence.
//  * consumer thread tid polls ITS OWN word statePk[(t-1)&1][b][tid] with
//    relaxed-agent loads until tag==t-1; the successful poll load already
//    carries the value -> zero extra latency after detection. This removes
//    three IF round-trips/step vs v2 (ack-before-flag, flag propagate,
//    separate state load).
//  * sh_state is double-buffered in LDS -> ONE __syncthreads per step.
//  * WAR safety: a word tagged t-1 implies its block passed barrier(t-1),
//    which implies all that block's threads completed poll(t-2). So when any
//    block reaches step t and overwrites slot[t&1] (holding t-2 tags),
//    nobody can still be polling for t-2. Tag monotonicity per slot (t-2 ->
//    t) means '== t-1' polls never miss their value.
//  * bp is nontemporal write-once; ONE agent-release fence per block after
//    the loop, then done-flag = T_DIM; backtracker polls 8 done-flags,
//    acquire-fences, then reads bp with cached loads.
// ---------------------------------------------------------------------------
__global__ __launch_bounds__(512) void scan_kernel(
    const float* __restrict__ pot, const float* __restrict__ trT,
    unsigned long long* __restrict__ statePk,  // [2][B][U] {tag,value}
    unsigned int* __restrict__ flags,          // [B][NBLK] done-flags
    unsigned short* __restrict__ bp,           // [T-1][B][U]
    float* __restrict__ outv)                  // [B][T]
{
  const int blk = blockIdx.x;
  const int b = blk & (B_DIM - 1);
  const int j = blk >> 5;
  const int tid = threadIdx.x;
  const int u_local = tid >> 3;
  const int vseg = tid & 7;
  const int u = j * UB + u_local;

  __shared__ float sh_state[2][U_DIM];
  __shared__ float sh_v[U_DIM];
  __shared__ int sh_i[U_DIM];

  // load this thread's transition slice into registers (once)
  float4 trreg[16];
  const float* trRow = trT + (size_t)u * U_DIM;
#pragma unroll
  for (int m = 0; m < 16; ++m)
    trreg[m] = *(const float4*)(trRow + vseg * 4 + m * 32);

  const float* potb = pot + (size_t)b * T_DIM * U_DIM;
  unsigned long long* stb = statePk + (size_t)b * U_DIM;  // slot stride 2*B*U... see below
  // layout: statePk[slot*B*U + b*U + u]
  unsigned int* myflags = flags + b * NBLK;

  for (int t = 1; t < T_DIM; ++t) {
    const int cur = t & 1;
    // independent of peers: issue before the wait so latency hides under it
    float p_u = potb[(size_t)t * U_DIM + u];  // 8-lane broadcast

    if (t > 1) {
      // poll own word of state t-1; the load that detects also delivers data
      const unsigned int want = (unsigned int)(t - 1);
      unsigned long long w;
      do {
        w = __hip_atomic_load(
            &statePk[(size_t)((t - 1) & 1) * B_DIM * U_DIM +
                     (size_t)b * U_DIM + tid],
            __ATOMIC_RELAXED, __HIP_MEMORY_SCOPE_AGENT);
      } while ((unsigned int)(w >> 32) != want);
      sh_state[cur][tid] = __uint_as_float((unsigned int)w);
    } else {
      // t==1: state0 = potentials[:,0] (written by gemm kernel, same stream)
      sh_state[cur][tid] = potb[tid];
    }
    __syncthreads();  // the only barrier per step

    float best = -3.402823466e38f;
    int bi = 0;
#pragma unroll
    for (int m = 0; m < 16; ++m) {
      float4 st = *(const float4*)(&sh_state[cur][vseg * 4 + m * 32]);
      float4 trv = trreg[m];
      int vbase = vseg * 4 + m * 32;
      float s0 = st.x + trv.x;
      float s1 = st.y + trv.y;
      float s2 = st.z + trv.z;
      float s3 = st.w + trv.w;
      if (s0 > best) { best = s0; bi = vbase; }
      if (s1 > best) { best = s1; bi = vbase + 1; }
      if (s2 > best) { best = s2; bi = vbase + 2; }
      if (s3 > best) { best = s3; bi = vbase + 3; }
    }
    // combine the 8 vseg partials (lanes u_local*8 .. +7), first-max tie rule
#pragma unroll
    for (int d = 1; d < 8; d <<= 1) {
      float ob = __shfl_xor(best, d, 64);
      int oi = __shfl_xor(bi, d, 64);
      if (ob > best || (ob == best && oi < bi)) { best = ob; bi = oi; }
    }
    if (vseg == 0) {
      float ns = best + p_u;
      unsigned long long pw =
          ((unsigned long long)(unsigned int)t << 32) |
          (unsigned long long)__float_as_uint(ns);
      // fire-and-forget: the tagged word is both data and flag
      __hip_atomic_store(
          &statePk[(size_t)cur * B_DIM * U_DIM + (size_t)b * U_DIM + u], pw,
          __ATOMIC_RELAXED, __HIP_MEMORY_SCOPE_AGENT);
      __builtin_nontemporal_store(
          (unsigned short)bi,
          &bp[(size_t)(t - 1) * (B_DIM * U_DIM) + (size_t)b * U_DIM + u]);
    }
    // no trailing barrier: next iteration writes the OTHER sh_state slot,
    // and stragglers of this step only read THIS slot.
  }

  // One release fence per block (single wbl2): makes the nt bp stores
  // visible device-wide, then publish "done".
  __syncthreads();
  if (tid == 0) {
    __builtin_amdgcn_fence(__ATOMIC_RELEASE, "agent");
    __hip_atomic_store(&myflags[j], (unsigned int)T_DIM, __ATOMIC_RELAXED,
                       __HIP_MEMORY_SCOPE_AGENT);
  }

  // block j==0 of each batch: final argmax + backtrack
  if (j == 0) {
    if (tid < NBLK) {
      while (__hip_atomic_load(&myflags[tid], __ATOMIC_RELAXED,
                               __HIP_MEMORY_SCOPE_AGENT) < (unsigned)T_DIM) {}
    }
    __syncthreads();
    // one acquire fence: invalidate possibly-stale L1/L2 lines (bp was
    // written by remote blocks; ws poison from previous launch may linger)
    if (tid == 0) __builtin_amdgcn_fence(__ATOMIC_ACQUIRE, "agent");
    __syncthreads();

    {
      unsigned long long w = __hip_atomic_load(
          &statePk[(size_t)((T_DIM - 1) & 1) * B_DIM * U_DIM +
                   (size_t)b * U_DIM + tid],
          __ATOMIC_RELAXED, __HIP_MEMORY_SCOPE_AGENT);
      sh_v[tid] = __uint_as_float((unsigned int)w);
      sh_i[tid] = tid;
    }
    __syncthreads();
    for (int s = 256; s > 0; s >>= 1) {
      if (tid < s) {
        float a = sh_v[tid], c = sh_v[tid + s];
        int ia = sh_i[tid], ic = sh_i[tid + s];
        if (c > a || (c == a && ic < ia)) { sh_v[tid] = c; sh_i[tid] = ic; }
      }
      __syncthreads();
    }
    if (tid == 0) {
      int tag = sh_i[0];
      outv[(size_t)b * T_DIM + (T_DIM - 1)] = (float)tag;
      for (int t = T_DIM - 1; t >= 1; --t) {
        tag = bp[(size_t)(t - 1) * (B_DIM * U_DIM) + (size_t)b * U_DIM + tag];
        outv[(size_t)b * T_DIM + (t - 1)] = (float)tag;
      }
    }
  }
}

// ---------------------------------------------------------------------------
extern "C" void kernel_launch(void* const* d_in, const int* in_sizes, int n_in,
                              void* d_out, int out_size, void* d_ws, size_t ws_size,
                              hipStream_t stream)
{
  const float* x    = (const float*)d_in[0];
  const float* W    = (const float*)d_in[1];
  const float* bias = (const float*)d_in[2];
  const float* tr   = (const float*)d_in[3];
  const float* lb   = (const float*)d_in[4];
  const float* rb   = (const float*)d_in[5];

  float* out = (float*)d_out;
  float* out_v   = out;                                      // (B,T) viterbi tags
  float* out_pot = out + (size_t)B_DIM * T_DIM;              // (B,T,U) potentials
  float* out_seq = out_pot + (size_t)B_DIM * T_DIM * U_DIM;  // (B,) seq lengths
  float* out_tr  = out_seq + B_DIM;                          // (U,U) transitions

  // ws layout
  float* trT = (float*)d_ws;                                           // 1 MB
  unsigned long long* statePk =
      (unsigned long long*)(trT + (size_t)U_DIM * U_DIM);              // 256 KB
  unsigned int* flags = (unsigned int*)(statePk + 2 * B_DIM * U_DIM);  // 1 KB
  unsigned short* bp = (unsigned short*)(flags + B_DIM * NBLK);        // ~64 MB

  hipLaunchKernelGGL(init_kernel, dim3(128), dim3(256), 0, stream,
                     statePk, flags);
  hipLaunchKernelGGL(aux_kernel, dim3(1024), dim3(256), 0, stream,
                     tr, out_tr, trT, out_seq);
  hipLaunchKernelGGL(gemm_kernel, dim3(M_DIM / BM, U_DIM / BN), dim3(256), 0,
                     stream, x, W, bias, lb, rb, out_pot);
  hipLaunchKernelGGL(scan_kernel, dim3(NBLK * B_DIM), dim3(512), 0, stream,
                     out_pot, trT, statePk, flags, bp, out_v);
}